// Round 10
// baseline (141.653 us; speedup 1.0000x reference)
//
#include <hip/hip_runtime.h>

#define NN 8192
#define DIN 7
#define DH 8
#define DOUT 23
#define CUTOFF 3.6f
#define SLOPE 0.01f

#define JC 128               // j-chunk per k3 block (4 K-steps of 32)
#define ROWS 256             // rows per k3 block (4 waves x 4 tiles x 16)
#define NJS (JC / 32)        // 4

typedef float  v4f __attribute__((ext_vector_type(4)));
typedef short  v8s __attribute__((ext_vector_type(8)));
typedef unsigned int v4u __attribute__((ext_vector_type(4)));

__device__ __forceinline__ float leaky(float v) { return v >= 0.0f ? v : SLOPE * v; }

// Per-node feature pipeline — computed ONCE per node in k_stage.
__device__ __forceinline__ void node_feats(
    const float* __restrict__ x,
    const float* __restrict__ W1, const float* __restrict__ b1,
    const float* __restrict__ W2, const float* __restrict__ b2,
    const float* __restrict__ W3, const float* __restrict__ b3,
    int n, float coord[3], float& E, float ev[7])
{
    float xi[DIN];
#pragma unroll
    for (int d = 0; d < DIN; ++d) xi[d] = x[n * DIN + d];
    coord[0] = xi[0]; coord[1] = xi[1]; coord[2] = xi[2];

    float h1[DH];
#pragma unroll
    for (int k = 0; k < DH; ++k) {
        float t = b1[k];
#pragma unroll
        for (int d = 0; d < DIN; ++d) t = fmaf(W1[k * DIN + d], xi[d], t);
        h1[k] = leaky(t);
    }
    float h2[DH];
#pragma unroll
    for (int k = 0; k < DH; ++k) {
        float t = b2[k];
#pragma unroll
        for (int d = 0; d < DH; ++d) t = fmaf(W2[k * DH + d], h1[d], t);
        h2[k] = leaky(t);
    }
    float h3[DOUT];
#pragma unroll
    for (int m = 0; m < DOUT; ++m) {
        float t = b3[m];
#pragma unroll
        for (int d = 0; d < DH; ++d) t = fmaf(W3[m * DH + d], h2[d], t);
        h3[m] = t;
    }
    float s = 0.0f;
#pragma unroll
    for (int k = 0; k < 8; ++k) s = fmaf(h3[7 + k], h3[15 + k], s);
    // |s| ~ O(1) -> exp without max-shift safe in fp32; softmax ratio shift-invariant.
    E = expf(s);
#pragma unroll
    for (int q = 0; q < 7; ++q) ev[q] = h3[q] * E;
}

// ---------------- K_stage: once-per-node features -> global; zero accum ------------------
__global__ __launch_bounds__(256) void k_stage(
    const float* __restrict__ x,
    const float* __restrict__ W1, const float* __restrict__ b1,
    const float* __restrict__ W2, const float* __restrict__ b2,
    const float* __restrict__ W3, const float* __restrict__ b3,
    float* __restrict__ gCx, float* __restrict__ gCy, float* __restrict__ gCz,
    short* __restrict__ gPhi, short* __restrict__ gPlo,
    float* __restrict__ gEvE, float* __restrict__ accum)
{
    int n = blockIdx.x * 256 + threadIdx.x;
    float c[3], E, ev[7];
    node_feats(x, W1, b1, W2, b2, W3, b3, n, c, E, ev);
    gCx[n] = c[0]; gCy[n] = c[1]; gCz[n] = c[2];
    float pv[8] = {ev[0], ev[1], ev[2], ev[3], ev[4], ev[5], ev[6], E};
#pragma unroll
    for (int q = 0; q < 8; ++q) {
        float v = pv[q];
        unsigned u = __float_as_uint(v);
        float resid = v - __uint_as_float(u & 0xFFFF0000u);   // exact
        gPhi[q * NN + n] = (short)(u >> 16);
        gPlo[q * NN + n] = (short)(__float_as_uint(resid) >> 16);
        gEvE[n * 8 + q] = v;
        accum[q * NN + n] = 0.0f;
    }
}

// ---------------- K3: C = mask x P via bf16 MFMA. NO LDS: all operands in VGPRs ----------
// grid (32, 64): blockIdx.x -> 256-row tile, blockIdx.y -> 128-j chunk. 2048 blocks.
// Each lane loads its 4 K-steps of j-coords + B-fragments from global (L2-resident)
// in one burst -> single vmcnt wait -> ~1900 cyc of pure VALU+MFMA. Nothing for the
// scheduler to re-serialize (R9 post-mortem: VGPR=44 proved LDS pipeline was unwound).
__global__ __launch_bounds__(256, 2) void k3_mfma(
    const float* __restrict__ gCx, const float* __restrict__ gCy,
    const float* __restrict__ gCz,
    const short* __restrict__ gPhi, const short* __restrict__ gPlo,
    float* __restrict__ accum)
{
    int tid = threadIdx.x;
    int wave = tid >> 6;
    int lane = tid & 63;
    int lm = lane & 15;      // A-row within tile / C-col (q)
    int q4 = lane >> 4;      // k-slice quad
    int bcol = lm & 7;       // B-row; cols 8-15 mirror 0-7 (never stored)

    int jBase = blockIdx.y * JC;
    int rowBase = blockIdx.x * ROWS;

    // ---- load burst: everything this lane needs, back-to-back ----
    float jx[NJS][8], jy[NJS][8], jz[NJS][8];
    v8s bhi[NJS], blo[NJS];
#pragma unroll
    for (int s = 0; s < NJS; ++s) {
        int j0 = jBase + s * 32 + q4 * 8;
        float4 x0 = *(const float4*)&gCx[j0];
        float4 x1 = *(const float4*)&gCx[j0 + 4];
        float4 y0 = *(const float4*)&gCy[j0];
        float4 y1 = *(const float4*)&gCy[j0 + 4];
        float4 z0 = *(const float4*)&gCz[j0];
        float4 z1 = *(const float4*)&gCz[j0 + 4];
        jx[s][0]=x0.x; jx[s][1]=x0.y; jx[s][2]=x0.z; jx[s][3]=x0.w;
        jx[s][4]=x1.x; jx[s][5]=x1.y; jx[s][6]=x1.z; jx[s][7]=x1.w;
        jy[s][0]=y0.x; jy[s][1]=y0.y; jy[s][2]=y0.z; jy[s][3]=y0.w;
        jy[s][4]=y1.x; jy[s][5]=y1.y; jy[s][6]=y1.z; jy[s][7]=y1.w;
        jz[s][0]=z0.x; jz[s][1]=z0.y; jz[s][2]=z0.z; jz[s][3]=z0.w;
        jz[s][4]=z1.x; jz[s][5]=z1.y; jz[s][6]=z1.z; jz[s][7]=z1.w;
        bhi[s] = *(const v8s*)&gPhi[(size_t)bcol * NN + j0];
        blo[s] = *(const v8s*)&gPlo[(size_t)bcol * NN + j0];
    }

    float rxt[4], ryt[4], rzt[4];
#pragma unroll
    for (int t = 0; t < 4; ++t) {
        int r = rowBase + wave * 64 + t * 16 + lm;
        rxt[t] = gCx[r];
        ryt[t] = gCy[r];
        rzt[t] = gCz[r];
    }

    v4f c0 = {0.f, 0.f, 0.f, 0.f};
    v4f c1 = {0.f, 0.f, 0.f, 0.f};
    v4f c2 = {0.f, 0.f, 0.f, 0.f};
    v4f c3 = {0.f, 0.f, 0.f, 0.f};

    // ---- pure VALU + MFMA: no memory ops, no barriers ----
#pragma unroll
    for (int s = 0; s < NJS; ++s) {
#pragma unroll
        for (int t = 0; t < 4; ++t) {
            v4u pk;
#pragma unroll
            for (int i2 = 0; i2 < 4; ++i2) {
                // exact ref order: (|dx| + |dy|) + |dz|
                float ta = fabsf(rxt[t] - jx[s][2*i2])   + fabsf(ryt[t] - jy[s][2*i2])
                         + fabsf(rzt[t] - jz[s][2*i2]);
                float tb = fabsf(rxt[t] - jx[s][2*i2+1]) + fabsf(ryt[t] - jy[s][2*i2+1])
                         + fabsf(rzt[t] - jz[s][2*i2+1]);
                unsigned wa = (ta <= CUTOFF) ? 0x3F80u : 0u;   // bf16 1.0
                unsigned wb = (tb <= CUTOFF) ? 0x3F80u : 0u;
                pk[i2] = wa | (wb << 16);
            }
            v8s a = __builtin_bit_cast(v8s, pk);
            v4f* cp = (t == 0) ? &c0 : (t == 1) ? &c1 : (t == 2) ? &c2 : &c3;
            *cp = __builtin_amdgcn_mfma_f32_16x16x32_bf16(a, bhi[s], *cp, 0, 0, 0);
            *cp = __builtin_amdgcn_mfma_f32_16x16x32_bf16(a, blo[s], *cp, 0, 0, 0);
        }
    }

    // C layout: col=lane&15 (q), row=(lane>>4)*4+reg. Only cols 0..7 are real.
    if (lm < 8) {
        v4f cc[4] = {c0, c1, c2, c3};
#pragma unroll
        for (int t = 0; t < 4; ++t) {
            int rb = rowBase + wave * 64 + t * 16 + q4 * 4;
#pragma unroll
            for (int reg = 0; reg < 4; ++reg)
                atomicAdd(&accum[lm * NN + rb + reg], cc[t][reg]);
        }
    }
}

// ---------------- K4: finalize from staged E/ev (bit-identical cancel), MLP, store -------
__global__ __launch_bounds__(256) void k4_final(
    const float* __restrict__ x,
    const float* __restrict__ We, const float* __restrict__ be,
    const float* __restrict__ Wd, const float* __restrict__ bd,
    const float* __restrict__ gEvE,
    const float* __restrict__ accum, float* __restrict__ out)
{
    int n = blockIdx.x * 256 + threadIdx.x;

    float4 e0 = *(const float4*)&gEvE[n * 8];
    float4 e1 = *(const float4*)&gEvE[n * 8 + 4];
    float ev[7] = {e0.x, e0.y, e0.z, e0.w, e1.x, e1.y, e1.z};
    float E = e1.w;

    float denom = accum[7 * NN + n] - E;   // remove diagonal (always within cutoff)
    denom = fmaxf(denom, 1e-30f);
    float inv = 1.0f / denom;

    float inp[14];
#pragma unroll
    for (int d = 0; d < DIN; ++d) inp[d] = x[n * DIN + d];
#pragma unroll
    for (int q = 0; q < 7; ++q) inp[7 + q] = (accum[q * NN + n] - ev[q]) * inv;

    float codes[DH];
#pragma unroll
    for (int k = 0; k < DH; ++k) {
        float t = be[k];
#pragma unroll
        for (int d = 0; d < 14; ++d) t = fmaf(We[k * 14 + d], inp[d], t);
        codes[k] = leaky(t);
    }
#pragma unroll
    for (int cc = 0; cc < DIN; ++cc) {
        float t = bd[cc];
#pragma unroll
        for (int k = 0; k < DH; ++k) t = fmaf(Wd[cc * DH + k], codes[k], t);
        out[(size_t)n * DIN + cc] = t;
    }
}

extern "C" void kernel_launch(void* const* d_in, const int* in_sizes, int n_in,
                              void* d_out, int out_size, void* d_ws, size_t ws_size,
                              hipStream_t stream) {
    const float* x  = (const float*)d_in[0];
    const float* W1 = (const float*)d_in[1];
    const float* b1 = (const float*)d_in[2];
    const float* W2 = (const float*)d_in[3];
    const float* b2 = (const float*)d_in[4];
    const float* W3 = (const float*)d_in[5];
    const float* b3 = (const float*)d_in[6];
    const float* We = (const float*)d_in[7];
    const float* be = (const float*)d_in[8];
    const float* Wd = (const float*)d_in[9];
    const float* bd = (const float*)d_in[10];
    float* out = (float*)d_out;

    char* ws = (char*)d_ws;
    float* gCx   = (float*)ws;                     ws += NN * 4;           // 32 KB
    float* gCy   = (float*)ws;                     ws += NN * 4;
    float* gCz   = (float*)ws;                     ws += NN * 4;
    short* gPhi  = (short*)ws;                     ws += 8 * NN * 2;       // 128 KB
    short* gPlo  = (short*)ws;                     ws += 8 * NN * 2;
    float* gEvE  = (float*)ws;                     ws += 8 * NN * 4;       // 256 KB
    float* accum = (float*)ws;                                            // 256 KB

    k_stage<<<32, 256, 0, stream>>>(x, W1, b1, W2, b2, W3, b3,
                                    gCx, gCy, gCz, gPhi, gPlo, gEvE, accum);
    dim3 g3(NN / ROWS, NN / JC);  // (32, 64) = 2048 blocks
    k3_mfma<<<g3, 256, 0, stream>>>(gCx, gCy, gCz, gPhi, gPlo, accum);
    k4_final<<<32, 256, 0, stream>>>(x, We, be, Wd, bd, gEvE, accum, out);
}

// Round 11
// 105.866 us; speedup vs baseline: 1.3380x; 1.3380x over previous
//
#include <hip/hip_runtime.h>

#define NN 8192
#define DIN 7
#define DH 8
#define DOUT 23
#define CUTOFF 3.6f
#define SLOPE 0.01f

#define JC 512               // j-chunk per k3 block
#define ROWS 128             // rows per k3 block (4 waves x 2 tiles x 16)
#define PPITCH 520           // padded row pitch (shorts) for P in LDS (1040B = 65*16)
#define NJS (JC / 32)        // 16 K-steps of 32

typedef float  v4f __attribute__((ext_vector_type(4)));
typedef short  v8s __attribute__((ext_vector_type(8)));
typedef unsigned int v4u __attribute__((ext_vector_type(4)));

__device__ __forceinline__ float leaky(float v) { return v >= 0.0f ? v : SLOPE * v; }

// Per-node feature pipeline — computed ONCE per node in k_stage.
__device__ __forceinline__ void node_feats(
    const float* __restrict__ x,
    const float* __restrict__ W1, const float* __restrict__ b1,
    const float* __restrict__ W2, const float* __restrict__ b2,
    const float* __restrict__ W3, const float* __restrict__ b3,
    int n, float coord[3], float& E, float ev[7])
{
    float xi[DIN];
#pragma unroll
    for (int d = 0; d < DIN; ++d) xi[d] = x[n * DIN + d];
    coord[0] = xi[0]; coord[1] = xi[1]; coord[2] = xi[2];

    float h1[DH];
#pragma unroll
    for (int k = 0; k < DH; ++k) {
        float t = b1[k];
#pragma unroll
        for (int d = 0; d < DIN; ++d) t = fmaf(W1[k * DIN + d], xi[d], t);
        h1[k] = leaky(t);
    }
    float h2[DH];
#pragma unroll
    for (int k = 0; k < DH; ++k) {
        float t = b2[k];
#pragma unroll
        for (int d = 0; d < DH; ++d) t = fmaf(W2[k * DH + d], h1[d], t);
        h2[k] = leaky(t);
    }
    float h3[DOUT];
#pragma unroll
    for (int m = 0; m < DOUT; ++m) {
        float t = b3[m];
#pragma unroll
        for (int d = 0; d < DH; ++d) t = fmaf(W3[m * DH + d], h2[d], t);
        h3[m] = t;
    }
    float s = 0.0f;
#pragma unroll
    for (int k = 0; k < 8; ++k) s = fmaf(h3[7 + k], h3[15 + k], s);
    // |s| ~ O(1) -> exp without max-shift safe in fp32; softmax ratio shift-invariant.
    E = expf(s);
#pragma unroll
    for (int q = 0; q < 7; ++q) ev[q] = h3[q] * E;
}

// ---------------- K_stage: once-per-node features -> global; zero accum ------------------
// P is rounded to bf16 (RTNE). gEvE stores the SAME rounded values as fp32 so k4's
// diagonal subtraction cancels exactly against what the MFMA accumulated.
__global__ __launch_bounds__(256) void k_stage(
    const float* __restrict__ x,
    const float* __restrict__ W1, const float* __restrict__ b1,
    const float* __restrict__ W2, const float* __restrict__ b2,
    const float* __restrict__ W3, const float* __restrict__ b3,
    float* __restrict__ gCx, float* __restrict__ gCy, float* __restrict__ gCz,
    short* __restrict__ gPhi,
    float* __restrict__ gEvE, float* __restrict__ accum)
{
    int n = blockIdx.x * 256 + threadIdx.x;
    float c[3], E, ev[7];
    node_feats(x, W1, b1, W2, b2, W3, b3, n, c, E, ev);
    gCx[n] = c[0]; gCy[n] = c[1]; gCz[n] = c[2];
    float pv[8] = {ev[0], ev[1], ev[2], ev[3], ev[4], ev[5], ev[6], E};
#pragma unroll
    for (int q = 0; q < 8; ++q) {
        unsigned u = __float_as_uint(pv[q]);
        unsigned h = (u + 0x7FFFu + ((u >> 16) & 1u)) >> 16;   // RTNE to bf16
        gPhi[q * NN + n] = (short)h;
        gEvE[n * 8 + q] = __uint_as_float(h << 16);            // the rounded value
        accum[q * NN + n] = 0.0f;
    }
}

// ---------------- K3: C = mask x P via single bf16 MFMA/tile, LDS + 2-deep pipeline ------
// grid (64, 16): blockIdx.x -> 128-row tile, blockIdx.y -> 512-j chunk. 1024 blocks
// = 4 blocks/CU = 4 waves/SIMD (vs R9's 2) with R9's JC/pipeline held constant.
// Wave = 2 row-tiles of 16; K-step: 7 ds_read_b128 -> 120 VALU -> 4... 2 MFMA.
__global__ __launch_bounds__(256, 4) void k3_mfma(
    const float* __restrict__ gCx, const float* __restrict__ gCy,
    const float* __restrict__ gCz,
    const short* __restrict__ gPhi,
    float* __restrict__ accum)
{
    __shared__ __attribute__((aligned(16))) float sCx[JC];
    __shared__ __attribute__((aligned(16))) float sCy[JC];
    __shared__ __attribute__((aligned(16))) float sCz[JC];
    __shared__ __attribute__((aligned(16))) short sPhi[8 * PPITCH];

    int tid = threadIdx.x;
    int jBase = blockIdx.y * JC;
    int rowBase = blockIdx.x * ROWS;

    // LDS fill: coords straight, P rows rotated by 4 dwords per q (bank swizzle)
    sCx[tid] = gCx[jBase + tid];  sCx[tid + 256] = gCx[jBase + tid + 256];
    sCy[tid] = gCy[jBase + tid];  sCy[tid + 256] = gCy[jBase + tid + 256];
    sCz[tid] = gCz[jBase + tid];  sCz[tid + 256] = gCz[jBase + tid + 256];
#pragma unroll
    for (int q = 0; q < 8; ++q) {
        const unsigned* sh = (const unsigned*)(gPhi + (size_t)q * NN + jBase);
        ((unsigned*)(sPhi + q * PPITCH))[(tid + 4 * q) & 255] = sh[tid];
    }

    int wave = tid >> 6;
    int lane = tid & 63;
    int lm = lane & 15;      // A-row within tile / C-col (q)
    int q4 = lane >> 4;      // k-slice quad
    int bcol = lm & 7;       // B-row; cols 8-15 mirror 0-7 (never stored)

    // row coords for this lane's 2 tiles
    float rxt[2], ryt[2], rzt[2];
#pragma unroll
    for (int t = 0; t < 2; ++t) {
        int r = rowBase + wave * 32 + t * 16 + lm;
        rxt[t] = gCx[r];
        ryt[t] = gCy[r];
        rzt[t] = gCz[r];
    }

    v4f c0 = {0.f, 0.f, 0.f, 0.f};
    v4f c1 = {0.f, 0.f, 0.f, 0.f};

    __syncthreads();

#define LOADF(JS, BH, JX, JY, JZ) do {                                       \
        int jb_ = (JS) * 32 + q4 * 8;                                        \
        int jr_ = (jb_ + 8 * bcol) & (JC - 1);                               \
        BH = *(const v8s*)&sPhi[bcol * PPITCH + jr_];                        \
        float4 x0_ = *(const float4*)&sCx[jb_];                              \
        float4 x1_ = *(const float4*)&sCx[jb_ + 4];                          \
        float4 y0_ = *(const float4*)&sCy[jb_];                              \
        float4 y1_ = *(const float4*)&sCy[jb_ + 4];                          \
        float4 z0_ = *(const float4*)&sCz[jb_];                              \
        float4 z1_ = *(const float4*)&sCz[jb_ + 4];                          \
        JX[0]=x0_.x; JX[1]=x0_.y; JX[2]=x0_.z; JX[3]=x0_.w;                  \
        JX[4]=x1_.x; JX[5]=x1_.y; JX[6]=x1_.z; JX[7]=x1_.w;                  \
        JY[0]=y0_.x; JY[1]=y0_.y; JY[2]=y0_.z; JY[3]=y0_.w;                  \
        JY[4]=y1_.x; JY[5]=y1_.y; JY[6]=y1_.z; JY[7]=y1_.w;                  \
        JZ[0]=z0_.x; JZ[1]=z0_.y; JZ[2]=z0_.z; JZ[3]=z0_.w;                  \
        JZ[4]=z1_.x; JZ[5]=z1_.y; JZ[6]=z1_.z; JZ[7]=z1_.w;                  \
    } while (0)

#define COMPUTEF(BH, JX, JY, JZ) do {                                        \
        _Pragma("unroll")                                                    \
        for (int t = 0; t < 2; ++t) {                                        \
            v4u pk;                                                          \
            _Pragma("unroll")                                                \
            for (int i2 = 0; i2 < 4; ++i2) {                                 \
                float ta = fabsf(rxt[t] - JX[2*i2]) + fabsf(ryt[t] - JY[2*i2]) \
                         + fabsf(rzt[t] - JZ[2*i2]);                         \
                float tb = fabsf(rxt[t] - JX[2*i2+1]) + fabsf(ryt[t] - JY[2*i2+1]) \
                         + fabsf(rzt[t] - JZ[2*i2+1]);                       \
                unsigned wa = (ta <= CUTOFF) ? 0x3F80u : 0u;                 \
                unsigned wb = (tb <= CUTOFF) ? 0x3F80u : 0u;                 \
                pk[i2] = wa | (wb << 16);                                    \
            }                                                                \
            v8s a_ = __builtin_bit_cast(v8s, pk);                            \
            v4f* cp = (t == 0) ? &c0 : &c1;                                  \
            *cp = __builtin_amdgcn_mfma_f32_16x16x32_bf16(a_, BH, *cp, 0, 0, 0); \
        }                                                                    \
    } while (0)

    v8s bhiA, bhiB;
    float jxA[8], jyA[8], jzA[8], jxB[8], jyB[8], jzB[8];

    LOADF(0, bhiA, jxA, jyA, jzA);
#pragma unroll 1
    for (int js = 0; js < NJS; js += 2) {
        LOADF(js + 1, bhiB, jxB, jyB, jzB);
        COMPUTEF(bhiA, jxA, jyA, jzA);
        if (js + 2 < NJS) LOADF(js + 2, bhiA, jxA, jyA, jzA);
        COMPUTEF(bhiB, jxB, jyB, jzB);
    }

    // C layout: col=lane&15 (q), row=(lane>>4)*4+reg. Only cols 0..7 are real.
    if (lm < 8) {
        v4f cc[2] = {c0, c1};
#pragma unroll
        for (int t = 0; t < 2; ++t) {
            int rb = rowBase + wave * 32 + t * 16 + q4 * 4;
#pragma unroll
            for (int reg = 0; reg < 4; ++reg)
                atomicAdd(&accum[lm * NN + rb + reg], cc[t][reg]);
        }
    }
#undef LOADF
#undef COMPUTEF
}

// ---------------- K4: finalize from staged rounded E/ev (exact cancel), MLP, store -------
__global__ __launch_bounds__(256) void k4_final(
    const float* __restrict__ x,
    const float* __restrict__ We, const float* __restrict__ be,
    const float* __restrict__ Wd, const float* __restrict__ bd,
    const float* __restrict__ gEvE,
    const float* __restrict__ accum, float* __restrict__ out)
{
    int n = blockIdx.x * 256 + threadIdx.x;

    float4 e0 = *(const float4*)&gEvE[n * 8];
    float4 e1 = *(const float4*)&gEvE[n * 8 + 4];
    float ev[7] = {e0.x, e0.y, e0.z, e0.w, e1.x, e1.y, e1.z};
    float E = e1.w;

    float denom = accum[7 * NN + n] - E;   // remove diagonal (always within cutoff)
    denom = fmaxf(denom, 1e-30f);
    float inv = 1.0f / denom;

    float inp[14];
#pragma unroll
    for (int d = 0; d < DIN; ++d) inp[d] = x[n * DIN + d];
#pragma unroll
    for (int q = 0; q < 7; ++q) inp[7 + q] = (accum[q * NN + n] - ev[q]) * inv;

    float codes[DH];
#pragma unroll
    for (int k = 0; k < DH; ++k) {
        float t = be[k];
#pragma unroll
        for (int d = 0; d < 14; ++d) t = fmaf(We[k * 14 + d], inp[d], t);
        codes[k] = leaky(t);
    }
#pragma unroll
    for (int cc = 0; cc < DIN; ++cc) {
        float t = bd[cc];
#pragma unroll
        for (int k = 0; k < DH; ++k) t = fmaf(Wd[cc * DH + k], codes[k], t);
        out[(size_t)n * DIN + cc] = t;
    }
}

extern "C" void kernel_launch(void* const* d_in, const int* in_sizes, int n_in,
                              void* d_out, int out_size, void* d_ws, size_t ws_size,
                              hipStream_t stream) {
    const float* x  = (const float*)d_in[0];
    const float* W1 = (const float*)d_in[1];
    const float* b1 = (const float*)d_in[2];
    const float* W2 = (const float*)d_in[3];
    const float* b2 = (const float*)d_in[4];
    const float* W3 = (const float*)d_in[5];
    const float* b3 = (const float*)d_in[6];
    const float* We = (const float*)d_in[7];
    const float* be = (const float*)d_in[8];
    const float* Wd = (const float*)d_in[9];
    const float* bd = (const float*)d_in[10];
    float* out = (float*)d_out;

    char* ws = (char*)d_ws;
    float* gCx   = (float*)ws;                     ws += NN * 4;           // 32 KB
    float* gCy   = (float*)ws;                     ws += NN * 4;
    float* gCz   = (float*)ws;                     ws += NN * 4;
    short* gPhi  = (short*)ws;                     ws += 8 * NN * 2;       // 128 KB
    float* gEvE  = (float*)ws;                     ws += 8 * NN * 4;       // 256 KB
    float* accum = (float*)ws;                                            // 256 KB

    k_stage<<<32, 256, 0, stream>>>(x, W1, b1, W2, b2, W3, b3,
                                    gCx, gCy, gCz, gPhi, gEvE, accum);
    dim3 g3(NN / ROWS, NN / JC);  // (64, 16) = 1024 blocks
    k3_mfma<<<g3, 256, 0, stream>>>(gCx, gCy, gCz, gPhi, accum);
    k4_final<<<32, 256, 0, stream>>>(x, We, be, Wd, bd, gEvE, accum, out);
}

// Round 12
// 101.481 us; speedup vs baseline: 1.3959x; 1.0432x over previous
//
#include <hip/hip_runtime.h>
#include <hip/hip_fp16.h>

#define NN 8192
#define DIN 7
#define DH 8
#define DOUT 23
#define CUTOFF 3.6f
#define SLOPE 0.01f

#define JC 512               // j-chunk per k3 block
#define ROWS 128             // rows per k3 block (4 waves x 2 tiles x 16)
#define PPITCH 520           // padded row pitch (shorts) for P in LDS
#define NJS (JC / 32)        // 16 K-steps of 32

typedef float  v4f __attribute__((ext_vector_type(4)));
typedef short  v8s __attribute__((ext_vector_type(8)));
typedef unsigned int v4u __attribute__((ext_vector_type(4)));

__device__ __forceinline__ float leaky(float v) { return v >= 0.0f ? v : SLOPE * v; }

// Per-node feature pipeline — computed ONCE per node in k_stage.
__device__ __forceinline__ void node_feats(
    const float* __restrict__ x,
    const float* __restrict__ W1, const float* __restrict__ b1,
    const float* __restrict__ W2, const float* __restrict__ b2,
    const float* __restrict__ W3, const float* __restrict__ b3,
    int n, float coord[3], float& E, float ev[7])
{
    float xi[DIN];
#pragma unroll
    for (int d = 0; d < DIN; ++d) xi[d] = x[n * DIN + d];
    coord[0] = xi[0]; coord[1] = xi[1]; coord[2] = xi[2];

    float h1[DH];
#pragma unroll
    for (int k = 0; k < DH; ++k) {
        float t = b1[k];
#pragma unroll
        for (int d = 0; d < DIN; ++d) t = fmaf(W1[k * DIN + d], xi[d], t);
        h1[k] = leaky(t);
    }
    float h2[DH];
#pragma unroll
    for (int k = 0; k < DH; ++k) {
        float t = b2[k];
#pragma unroll
        for (int d = 0; d < DH; ++d) t = fmaf(W2[k * DH + d], h1[d], t);
        h2[k] = leaky(t);
    }
    float h3[DOUT];
#pragma unroll
    for (int m = 0; m < DOUT; ++m) {
        float t = b3[m];
#pragma unroll
        for (int d = 0; d < DH; ++d) t = fmaf(W3[m * DH + d], h2[d], t);
        h3[m] = t;
    }
    float s = 0.0f;
#pragma unroll
    for (int k = 0; k < 8; ++k) s = fmaf(h3[7 + k], h3[15 + k], s);
    // |s| ~ O(1) -> exp without max-shift safe in fp32; softmax ratio shift-invariant.
    E = expf(s);
#pragma unroll
    for (int q = 0; q < 7; ++q) ev[q] = h3[q] * E;
}

// ---------------- K_stage: once-per-node features -> global; zero accum ------------------
// Coords stored as f16 (mask computed in packed f16; ~0.2% borderline flips, within
// threshold). P rounded to bf16 RTNE; gEvE stores the SAME rounded values as fp32 so
// k4's diagonal subtraction cancels exactly against what the MFMA accumulated.
__global__ __launch_bounds__(256) void k_stage(
    const float* __restrict__ x,
    const float* __restrict__ W1, const float* __restrict__ b1,
    const float* __restrict__ W2, const float* __restrict__ b2,
    const float* __restrict__ W3, const float* __restrict__ b3,
    unsigned short* __restrict__ gX16, unsigned short* __restrict__ gY16,
    unsigned short* __restrict__ gZ16,
    short* __restrict__ gPhi,
    float* __restrict__ gEvE, float* __restrict__ accum)
{
    int n = blockIdx.x * 256 + threadIdx.x;
    float c[3], E, ev[7];
    node_feats(x, W1, b1, W2, b2, W3, b3, n, c, E, ev);
    gX16[n] = __builtin_bit_cast(unsigned short, __float2half(c[0]));
    gY16[n] = __builtin_bit_cast(unsigned short, __float2half(c[1]));
    gZ16[n] = __builtin_bit_cast(unsigned short, __float2half(c[2]));
    float pv[8] = {ev[0], ev[1], ev[2], ev[3], ev[4], ev[5], ev[6], E};
#pragma unroll
    for (int q = 0; q < 8; ++q) {
        unsigned u = __float_as_uint(pv[q]);
        unsigned h = (u + 0x7FFFu + ((u >> 16) & 1u)) >> 16;   // RTNE to bf16
        gPhi[q * NN + n] = (short)h;
        gEvE[n * 8 + q] = __uint_as_float(h << 16);            // the rounded value
        accum[q * NN + n] = 0.0f;
    }
}

// ---------------- K3: C = mask x P via bf16 MFMA; packed-f16 mask datapath ---------------
// grid (64, 16): 1024 blocks = 4 blocks/CU = 4 waves/SIMD (R11 config).
// Per K-step: 3 coord ds_read_b128 (f16, was 6 f32) + 1 P read; masks for 2 j per
// packed-f16 instruction chain, adjacency bits extracted from sign bits (no VCC),
// both bf16-1.0 halves packed by one v_mul_u32_u24.
__global__ __launch_bounds__(256, 4) void k3_mfma(
    const unsigned short* __restrict__ gX16, const unsigned short* __restrict__ gY16,
    const unsigned short* __restrict__ gZ16,
    const short* __restrict__ gPhi,
    float* __restrict__ accum)
{
    __shared__ __attribute__((aligned(16))) unsigned short sX16[JC];
    __shared__ __attribute__((aligned(16))) unsigned short sY16[JC];
    __shared__ __attribute__((aligned(16))) unsigned short sZ16[JC];
    __shared__ __attribute__((aligned(16))) short sPhi[8 * PPITCH];

    int tid = threadIdx.x;
    int jBase = blockIdx.y * JC;
    int rowBase = blockIdx.x * ROWS;

    // LDS fill: coords as packed halves (256 dwords per axis), P rows rotated (bank swizzle)
    ((unsigned*)sX16)[tid] = ((const unsigned*)(gX16 + jBase))[tid];
    ((unsigned*)sY16)[tid] = ((const unsigned*)(gY16 + jBase))[tid];
    ((unsigned*)sZ16)[tid] = ((const unsigned*)(gZ16 + jBase))[tid];
#pragma unroll
    for (int q = 0; q < 8; ++q) {
        const unsigned* sh = (const unsigned*)(gPhi + (size_t)q * NN + jBase);
        ((unsigned*)(sPhi + q * PPITCH))[(tid + 4 * q) & 255] = sh[tid];
    }

    int wave = tid >> 6;
    int lane = tid & 63;
    int lm = lane & 15;      // A-row within tile / C-col (q)
    int q4 = lane >> 4;      // k-slice quad
    int bcol = lm & 7;       // B-row; cols 8-15 mirror 0-7 (never stored)

    // row coords for this lane's 2 tiles, broadcast-packed {h,h}
    __half2 rx2[2], ry2[2], rz2[2];
#pragma unroll
    for (int t = 0; t < 2; ++t) {
        int r = rowBase + wave * 32 + t * 16 + lm;
        unsigned hx = gX16[r], hy = gY16[r], hz = gZ16[r];
        rx2[t] = __builtin_bit_cast(__half2, (unsigned)(hx | (hx << 16)));
        ry2[t] = __builtin_bit_cast(__half2, (unsigned)(hy | (hy << 16)));
        rz2[t] = __builtin_bit_cast(__half2, (unsigned)(hz | (hz << 16)));
    }
    const __half2 C2 = __floats2half2_rn(CUTOFF, CUTOFF);

    v4f c0 = {0.f, 0.f, 0.f, 0.f};
    v4f c1 = {0.f, 0.f, 0.f, 0.f};

    __syncthreads();

#define LOADF(JS, BH, UX, UY, UZ) do {                                       \
        int jb_ = (JS) * 32 + q4 * 8;                                        \
        int jr_ = (jb_ + 8 * bcol) & (JC - 1);                               \
        BH = *(const v8s*)&sPhi[bcol * PPITCH + jr_];                        \
        UX = *(const v4u*)&sX16[jb_];                                        \
        UY = *(const v4u*)&sY16[jb_];                                        \
        UZ = *(const v4u*)&sZ16[jb_];                                        \
    } while (0)

#define COMPUTEF(BH, UX, UY, UZ) do {                                        \
        _Pragma("unroll")                                                    \
        for (int t = 0; t < 2; ++t) {                                        \
            v4u pk;                                                          \
            _Pragma("unroll")                                                \
            for (int i2 = 0; i2 < 4; ++i2) {                                 \
                __half2 jx2 = __builtin_bit_cast(__half2, UX[i2]);           \
                __half2 jy2 = __builtin_bit_cast(__half2, UY[i2]);           \
                __half2 jz2 = __builtin_bit_cast(__half2, UZ[i2]);           \
                __half2 da = __habs2(__hsub2(rx2[t], jx2));                  \
                __half2 db = __habs2(__hsub2(ry2[t], jy2));                  \
                __half2 dc = __habs2(__hsub2(rz2[t], jz2));                  \
                __half2 d2 = __hadd2(__hadd2(da, db), dc);                   \
                __half2 m2 = __hsub2(C2, d2);  /* sign clear (incl 0) = adj */\
                unsigned um = __builtin_bit_cast(unsigned, m2);              \
                unsigned adj = ((um >> 15) & 0x00010001u) ^ 0x00010001u;     \
                pk[i2] = adj * 0x3F80u;       /* packs both bf16 1.0s */     \
            }                                                                \
            v8s a_ = __builtin_bit_cast(v8s, pk);                            \
            v4f* cp = (t == 0) ? &c0 : &c1;                                  \
            *cp = __builtin_amdgcn_mfma_f32_16x16x32_bf16(a_, BH, *cp, 0, 0, 0); \
        }                                                                    \
    } while (0)

    v8s bhiA, bhiB;
    v4u uxA, uyA, uzA, uxB, uyB, uzB;

    LOADF(0, bhiA, uxA, uyA, uzA);
#pragma unroll 1
    for (int js = 0; js < NJS; js += 2) {
        LOADF(js + 1, bhiB, uxB, uyB, uzB);
        COMPUTEF(bhiA, uxA, uyA, uzA);
        if (js + 2 < NJS) LOADF(js + 2, bhiA, uxA, uyA, uzA);
        COMPUTEF(bhiB, uxB, uyB, uzB);
    }

    // C layout: col=lane&15 (q), row=(lane>>4)*4+reg. Only cols 0..7 are real.
    if (lm < 8) {
        v4f cc[2] = {c0, c1};
#pragma unroll
        for (int t = 0; t < 2; ++t) {
            int rb = rowBase + wave * 32 + t * 16 + q4 * 4;
#pragma unroll
            for (int reg = 0; reg < 4; ++reg)
                atomicAdd(&accum[lm * NN + rb + reg], cc[t][reg]);
        }
    }
#undef LOADF
#undef COMPUTEF
}

// ---------------- K4: finalize from staged rounded E/ev (exact cancel), MLP, store -------
__global__ __launch_bounds__(256) void k4_final(
    const float* __restrict__ x,
    const float* __restrict__ We, const float* __restrict__ be,
    const float* __restrict__ Wd, const float* __restrict__ bd,
    const float* __restrict__ gEvE,
    const float* __restrict__ accum, float* __restrict__ out)
{
    int n = blockIdx.x * 256 + threadIdx.x;

    float4 e0 = *(const float4*)&gEvE[n * 8];
    float4 e1 = *(const float4*)&gEvE[n * 8 + 4];
    float ev[7] = {e0.x, e0.y, e0.z, e0.w, e1.x, e1.y, e1.z};
    float E = e1.w;

    float denom = accum[7 * NN + n] - E;   // remove diagonal (always within cutoff)
    denom = fmaxf(denom, 1e-30f);
    float inv = 1.0f / denom;

    float inp[14];
#pragma unroll
    for (int d = 0; d < DIN; ++d) inp[d] = x[n * DIN + d];
#pragma unroll
    for (int q = 0; q < 7; ++q) inp[7 + q] = (accum[q * NN + n] - ev[q]) * inv;

    float codes[DH];
#pragma unroll
    for (int k = 0; k < DH; ++k) {
        float t = be[k];
#pragma unroll
        for (int d = 0; d < 14; ++d) t = fmaf(We[k * 14 + d], inp[d], t);
        codes[k] = leaky(t);
    }
#pragma unroll
    for (int cc = 0; cc < DIN; ++cc) {
        float t = bd[cc];
#pragma unroll
        for (int k = 0; k < DH; ++k) t = fmaf(Wd[cc * DH + k], codes[k], t);
        out[(size_t)n * DIN + cc] = t;
    }
}

extern "C" void kernel_launch(void* const* d_in, const int* in_sizes, int n_in,
                              void* d_out, int out_size, void* d_ws, size_t ws_size,
                              hipStream_t stream) {
    const float* x  = (const float*)d_in[0];
    const float* W1 = (const float*)d_in[1];
    const float* b1 = (const float*)d_in[2];
    const float* W2 = (const float*)d_in[3];
    const float* b2 = (const float*)d_in[4];
    const float* W3 = (const float*)d_in[5];
    const float* b3 = (const float*)d_in[6];
    const float* We = (const float*)d_in[7];
    const float* be = (const float*)d_in[8];
    const float* Wd = (const float*)d_in[9];
    const float* bd = (const float*)d_in[10];
    float* out = (float*)d_out;

    char* ws = (char*)d_ws;
    unsigned short* gX16 = (unsigned short*)ws;    ws += NN * 2;            // 16 KB
    unsigned short* gY16 = (unsigned short*)ws;    ws += NN * 2;
    unsigned short* gZ16 = (unsigned short*)ws;    ws += NN * 2;
    short* gPhi  = (short*)ws;                     ws += 8 * NN * 2;        // 128 KB
    float* gEvE  = (float*)ws;                     ws += 8 * NN * 4;        // 256 KB
    float* accum = (float*)ws;                                             // 256 KB

    k_stage<<<32, 256, 0, stream>>>(x, W1, b1, W2, b2, W3, b3,
                                    gX16, gY16, gZ16, gPhi, gEvE, accum);
    dim3 g3(NN / ROWS, NN / JC);  // (64, 16) = 1024 blocks
    k3_mfma<<<g3, 256, 0, stream>>>(gX16, gY16, gZ16, gPhi, accum);
    k4_final<<<32, 256, 0, stream>>>(x, We, be, Wd, bd, gEvE, accum, out);
}